// Round 3
// baseline (77.170 us; speedup 1.0000x reference)
//
#include <hip/hip_runtime.h>
#include <math.h>

// R7: LDS-instruction-count attack.
// R6 null (76.5->76.4) despite Schur/init cuts => wave-0 serial phase is NOT
// the bottleneck. Model: matvec issues ~700 b128 LDS wave-instrs/CU
// (~8.4K cyc @12cyc/instr on the shared LDS pipe) -- dominant, untouched by R6.
// Changes:
//  1. us stored dim-separated (usx/usy/usz, stride-1 time): window refill =
//     3 b128 per 4 lags (was 4).
//  2. Tail rows 256..1023: 12 rows/thread, 4 waves (w0-3), pure-Lc coeffs.
//     Head rows 0..255: 4 rows/thread, 4 waves (w12-15), c<K select (R6 logic).
//     Window = circular 16/8-slot private array, g-loop fully unrolled =>
//     all indices compile-time (SROA, no scratch, no rotate movs).
//     LDS wave-instrs ~700 -> ~280.
//  3. Wave roles at w%4-balanced slots: each SIMD gets 1 tail + 1 head.
//  4. Schur lane-shift: dual-convention DPP probe (0x130 then 0x138 for
//     dst[l]=src[l+1]), bpermute fallback. K-truncation kept (R6-verified).

#define TM1 1023
#define NTH 1024
#define K0  128
#define CSTRIDE 129
#define USN 1024

__device__ __forceinline__ float bperm(int a, float v) {
    return __int_as_float(__builtin_amdgcn_ds_bpermute(a, __float_as_int(v)));
}
__device__ __forceinline__ float rdlane(float v, int s) {
    return __int_as_float(__builtin_amdgcn_readlane(__float_as_int(v), s));
}
template<int CTRL>
__device__ __forceinline__ float dppmov(float v) {
    return __int_as_float(__builtin_amdgcn_update_dpp(
        0, __float_as_int(v), CTRL, 0xF, 0xF, true));
}
template<int CTRL, int RM, bool BC>
__device__ __forceinline__ float dppadd(float s) {
    float t = __int_as_float(__builtin_amdgcn_update_dpp(
        0, __float_as_int(s), CTRL, RM, 0xF, BC));
    return s + t;
}
// wave64 inclusive add-scan via DPP (blog-canonical row_shr set), probed
__device__ __forceinline__ float dpp_scan(float s) {
    s = dppadd<0x111, 0xF, true >(s);   // row_shr:1
    s = dppadd<0x112, 0xF, true >(s);   // row_shr:2
    s = dppadd<0x114, 0xF, true >(s);   // row_shr:4
    s = dppadd<0x118, 0xF, true >(s);   // row_shr:8
    s = dppadd<0x142, 0xA, false>(s);   // row_bcast:15 -> rows 1,3
    s = dppadd<0x143, 0xC, false>(s);   // row_bcast:31 -> rows 2,3
    return s;
}

__global__ __launch_bounds__(NTH, 1)
void fbm_schur_kernel(const float* __restrict__ alpha,
                      const float* __restrict__ tau,
                      const float* __restrict__ diffusion,
                      const float* __restrict__ du,
                      float* __restrict__ out)
{
    const int b   = blockIdx.x;
    const int tid = threadIdx.x;
    const int w   = tid >> 6;
    const int l   = tid & 63;

    __shared__ float colDT[K0 * CSTRIDE];          // [lag][col] normalized, 66 KB
    __shared__ float usx[USN], usy[USN], usz[USN]; // du*sd dim-separated, 12 KB
    __shared__ float plx[4][1024], ply[4][1024], plz[4][1024]; // jq partials, 48 KB
    __shared__ float LcS[128];                     // converged normalized column
    __shared__ float wtot[48];

    const float sd = sqrtf(diffusion[b]);
    const float tv = tau[b];
    const int   K  = min(K0, (int)ceilf(tv) + 48); // r ~ e^{-(k-tau)}: <1e-16 beyond
    const float* dub = du + (size_t)b * (TM1 * 3);

    if (w > 0) {
        // ---- staging by waves 1..15 (wave 0 goes straight to init+Schur) ----
        for (int e = tid - 64; e < TM1 * 3; e += (NTH - 64)) {
            int t = e / 3, d = e - 3 * t;
            float v = dub[e] * sd;
            float* dst = (d == 0) ? usx : (d == 1) ? usy : usz;
            dst[t] = v;
        }
        if (tid == 64) { usx[1023] = 0.f; usy[1023] = 0.f; usz[1023] = 0.f; }
    } else {
        // ---- generator init: p[k]=k^a shared across lanes (2 f64 pows/lane) ----
        const double a  = (double)alpha[b];
        const double tb = (double)tv;
        double pa = pow((double)(l == 0 ? 128 : l), a);  // lane0 holds p[128]
        double pb = pow((double)(l + 64), a);
        double pam1 = __shfl_up(pa, 1);                  // p[l-1]
        double pap1 = __shfl_down(pa, 1);                // p[l+1]
        double pbm1 = __shfl_up(pb, 1);                  // p[l+63]
        double pbp1 = __shfl_down(pb, 1);                // p[l+65]
        double p63  = __shfl(pa, 63);
        double p64  = __shfl(pb, 0);
        double p128 = __shfl(pa, 0);
        if (l == 1)  pam1 = 0.0;                         // p[0] = 0
        if (l == 63) pap1 = p64;
        if (l == 0)  pbm1 = p63;
        if (l == 63) pbp1 = p128;
        auto covk = [&](int k, double pm, double p0, double pp) -> float {
            if (k == 0) return 1.0f;
            double ck = 0.5 * (pp + pm - 2.0 * p0);
            double dk = (double)k;
            if (dk >= tb) ck *= exp(tb - dk);
            return (float)ck;
        };
        float g1a = covk(l,      pam1, (l == 0 ? 0.0 : pa), pap1);
        float g1b = covk(l + 64, pbm1, pb,                  pbp1);
        float g2a = (l == 0) ? 0.f : g1a;
        float g2b = g1b;

        // Dual-convention DPP probe for dst[l] = src[l+1]; bpermute fallback.
        int p130 = __builtin_amdgcn_update_dpp(0, l + 100, 0x130, 0xF, 0xF, true);
        const bool ok130 = (__builtin_amdgcn_readlane(p130, 5) == 106);
        int p138 = __builtin_amdgcn_update_dpp(0, l + 100, 0x138, 0xF, 0xF, true);
        const bool ok138 = (__builtin_amdgcn_readlane(p138, 5) == 106);
        const int addr_up = ((l + 1) & 63) << 2;

        // ---- serial Schur, K steps; scalar den recursion (rcp/rsqrt one step
        //      ahead, off the critical path). Writes [lag][col], stride 129. ----
        float den = 1.0f, rcpden = 1.0f, sc = 1.0f;     // den_0 = cov(0) = 1
#define SCHUR_LOOP(SHA, SHB)                                               \
        for (int k = 0; k < K; ++k) {                                      \
            colDT[l * CSTRIDE + k]        = g1a * sc;                      \
            colDT[(64 + l) * CSTRIDE + k] = g1b * sc;                      \
            float num  = rdlane(g2a, 1);                                   \
            float r    = num * rcpden;                                     \
            float wrap = rdlane(g2b, 0);                                   \
            float g2pa = (SHA);                                            \
            float g2pb = (SHB);                                            \
            if (l == 63) { g2pa = wrap; g2pb = 0.f; }                      \
            float n1a = fmaf(-r, g2pa, g1a);                               \
            float n1b = fmaf(-r, g2pb, g1b);                               \
            g2a = fmaf(-r, g1a, g2pa);                                     \
            g2b = fmaf(-r, g1b, g2pb);                                     \
            g1a = n1a; g1b = n1b;                                          \
            den    = fmaf(-r, num, den);                                   \
            rcpden = __builtin_amdgcn_rcpf(den);                           \
            sc     = __frsqrt_rn(den);                                     \
        }
        if (ok130)      { SCHUR_LOOP(dppmov<0x130>(g2a), dppmov<0x130>(g2b)) }
        else if (ok138) { SCHUR_LOOP(dppmov<0x138>(g2a), dppmov<0x138>(g2b)) }
        else            { SCHUR_LOOP(bperm(addr_up, g2a), bperm(addr_up, g2b)) }
#undef SCHUR_LOOP
        LcS[l]      = g1a * sc;      // sc == rsqrt(den_K)
        LcS[64 + l] = g1b * sc;
    }
    __syncthreads();

    const float lca = LcS[l], lcb = LcS[64 + l];

    if (w < 4) {
        // ---- TAIL: rows 256..1023, 12 rows/lane, pure-Lc FIR, wave = jq ----
        const int jq = w, j0 = jq << 5;
        const int B  = 256 + 12 * l;
        const int G  = max(0, min(8, (K - j0 + 3) >> 2));
        const float lsel = (jq < 2) ? lca : lcb;
        const int t00 = B - j0 - 4;                 // >= 156, always valid
        float wx[16], wy[16], wz[16];
        #pragma unroll
        for (int bk = 0; bk < 4; ++bk) {            // initial window d = 0..15
            float4 vx = *(const float4*)&usx[t00 + 4 * bk];
            float4 vy = *(const float4*)&usy[t00 + 4 * bk];
            float4 vz = *(const float4*)&usz[t00 + 4 * bk];
            wx[4*bk]=vx.x; wx[4*bk+1]=vx.y; wx[4*bk+2]=vx.z; wx[4*bk+3]=vx.w;
            wy[4*bk]=vy.x; wy[4*bk+1]=vy.y; wy[4*bk+2]=vy.z; wy[4*bk+3]=vy.w;
            wz[4*bk]=vz.x; wz[4*bk+1]=vz.y; wz[4*bk+2]=vz.z; wz[4*bk+3]=vz.w;
        }
        float ax[12], ay[12], az[12];
        #pragma unroll
        for (int i = 0; i < 12; ++i) { ax[i]=0.f; ay[i]=0.f; az[i]=0.f; }

        #pragma unroll
        for (int g = 0; g < 8; ++g) {
            if (g < G) {
                const int jg = j0 + 4 * g;
                #pragma unroll
                for (int s = 0; s < 4; ++s) {
                    float lc = rdlane(lsel, (jg + s) & 63);
                    #pragma unroll
                    for (int i = 0; i < 12; ++i) {
                        const int dd = ((i - s + 4 - 4 * g) + 64) & 15;
                        ax[i] = fmaf(lc, wx[dd], ax[i]);
                        ay[i] = fmaf(lc, wy[dd], ay[i]);
                        az[i] = fmaf(lc, wz[dd], az[i]);
                    }
                }
                {   // refill oldest 4 slots with block at t00-4(g+1) (>=124, valid)
                    const int tnb = t00 - 4 * (g + 1);
                    const int s0  = ((-4 * (g + 1)) + 64) & 15;   // in {12,8,4,0,...}
                    float4 vx = *(const float4*)&usx[tnb];
                    float4 vy = *(const float4*)&usy[tnb];
                    float4 vz = *(const float4*)&usz[tnb];
                    wx[s0]=vx.x; wx[s0+1]=vx.y; wx[s0+2]=vx.z; wx[s0+3]=vx.w;
                    wy[s0]=vy.x; wy[s0+1]=vy.y; wy[s0+2]=vy.z; wy[s0+3]=vy.w;
                    wz[s0]=vz.x; wz[s0+1]=vz.y; wz[s0+2]=vz.z; wz[s0+3]=vz.w;
                }
            }
        }
        #pragma unroll
        for (int r4 = 0; r4 < 3; ++r4) {
            *(float4*)&plx[jq][B + 4*r4] = make_float4(ax[4*r4],ax[4*r4+1],ax[4*r4+2],ax[4*r4+3]);
            *(float4*)&ply[jq][B + 4*r4] = make_float4(ay[4*r4],ay[4*r4+1],ay[4*r4+2],ay[4*r4+3]);
            *(float4*)&plz[jq][B + 4*r4] = make_float4(az[4*r4],az[4*r4+1],az[4*r4+2],az[4*r4+3]);
        }
    } else if (w >= 12) {
        // ---- HEAD: rows 0..255, 4 rows/lane, c<K select (R6 logic), wave = jq ----
        const int jq = w - 12, j0 = jq << 5;
        const int B  = l << 2;
        const int G  = max(0, min(8, (K - j0 + 3) >> 2));
        const float lsel = (jq < 2) ? lca : lcb;
        const unsigned Ku = (unsigned)K;
        const int t00 = B - j0 - 4;                 // may be negative -> masked
        float wx[8], wy[8], wz[8];
        #pragma unroll
        for (int bk = 0; bk < 2; ++bk) {
            const int tb = t00 + 4 * bk;
            const int tc = max(tb, 0);              // stays 16B-aligned
            float4 vx = *(const float4*)&usx[tc];
            float4 vy = *(const float4*)&usy[tc];
            float4 vz = *(const float4*)&usz[tc];
            const bool ok = tb >= 0;
            wx[4*bk]=ok?vx.x:0.f; wx[4*bk+1]=ok?vx.y:0.f; wx[4*bk+2]=ok?vx.z:0.f; wx[4*bk+3]=ok?vx.w:0.f;
            wy[4*bk]=ok?vy.x:0.f; wy[4*bk+1]=ok?vy.y:0.f; wy[4*bk+2]=ok?vy.z:0.f; wy[4*bk+3]=ok?vy.w:0.f;
            wz[4*bk]=ok?vz.x:0.f; wz[4*bk+1]=ok?vz.y:0.f; wz[4*bk+2]=ok?vz.z:0.f; wz[4*bk+3]=ok?vz.w:0.f;
        }
        float ax[4], ay[4], az[4];
        #pragma unroll
        for (int i = 0; i < 4; ++i) { ax[i]=0.f; ay[i]=0.f; az[i]=0.f; }

        #pragma unroll
        for (int g = 0; g < 8; ++g) {
            if (g < G) {
                const int jg = j0 + 4 * g;
                #pragma unroll
                for (int s = 0; s < 4; ++s) {
                    const int j = jg + s;
                    float lc = rdlane(lsel, j & 63);
                    // dword addr 128j+B = 129j + (B-j): 16B-aligned, lane stride 4
                    float4 h = *(const float4*)&colDT[(j << 7) + B];
                    const int p = B - j;
                    float c0 = ((unsigned)(p + 0) < Ku) ? h.x : lc;
                    float c1 = ((unsigned)(p + 1) < Ku) ? h.y : lc;
                    float c2 = ((unsigned)(p + 2) < Ku) ? h.z : lc;
                    float c3 = ((unsigned)(p + 3) < Ku) ? h.w : lc;
                    const int d0 = ((0 - s + 4 - 4 * g) + 64) & 7;
                    const int d1 = ((1 - s + 4 - 4 * g) + 64) & 7;
                    const int d2 = ((2 - s + 4 - 4 * g) + 64) & 7;
                    const int d3 = ((3 - s + 4 - 4 * g) + 64) & 7;
                    ax[0]=fmaf(c0,wx[d0],ax[0]); ay[0]=fmaf(c0,wy[d0],ay[0]); az[0]=fmaf(c0,wz[d0],az[0]);
                    ax[1]=fmaf(c1,wx[d1],ax[1]); ay[1]=fmaf(c1,wy[d1],ay[1]); az[1]=fmaf(c1,wz[d1],az[1]);
                    ax[2]=fmaf(c2,wx[d2],ax[2]); ay[2]=fmaf(c2,wy[d2],ay[2]); az[2]=fmaf(c2,wz[d2],az[2]);
                    ax[3]=fmaf(c3,wx[d3],ax[3]); ay[3]=fmaf(c3,wy[d3],ay[3]); az[3]=fmaf(c3,wz[d3],az[3]);
                }
                {   // refill 4 slots; base may be negative -> zero
                    const int tnb = t00 - 4 * (g + 1);
                    const int tc  = max(tnb, 0);
                    const int s0  = ((-4 * (g + 1)) + 64) & 7;    // in {4,0,4,0,...}
                    float4 vx = *(const float4*)&usx[tc];
                    float4 vy = *(const float4*)&usy[tc];
                    float4 vz = *(const float4*)&usz[tc];
                    const bool ok = tnb >= 0;
                    wx[s0]=ok?vx.x:0.f; wx[s0+1]=ok?vx.y:0.f; wx[s0+2]=ok?vx.z:0.f; wx[s0+3]=ok?vx.w:0.f;
                    wy[s0]=ok?vy.x:0.f; wy[s0+1]=ok?vy.y:0.f; wy[s0+2]=ok?vy.z:0.f; wy[s0+3]=ok?vy.w:0.f;
                    wz[s0]=ok?vz.x:0.f; wz[s0+1]=ok?vz.y:0.f; wz[s0+2]=ok?vz.z:0.f; wz[s0+3]=ok?vz.w:0.f;
                }
            }
        }
        *(float4*)&plx[jq][B] = make_float4(ax[0], ax[1], ax[2], ax[3]);
        *(float4*)&ply[jq][B] = make_float4(ay[0], ay[1], ay[2], ay[3]);
        *(float4*)&plz[jq][B] = make_float4(az[0], az[1], az[2], az[3]);
    }
    // waves 4..11 idle through the matvec
    __syncthreads();

    // ---- fused: sum jq planes + 16-wave scan + output ----
    const int i = tid;
    float sx = 0.f, sy = 0.f, sz = 0.f;
    if (i < TM1) {
        sx = plx[0][i] + plx[1][i] + plx[2][i] + plx[3][i];
        sy = ply[0][i] + ply[1][i] + ply[2][i] + ply[3][i];
        sz = plz[0][i] + plz[1][i] + plz[2][i] + plz[3][i];
    }
    {
        float pv = dpp_scan(1.0f);
        const bool scan_ok = (rdlane(pv, 63) == 64.0f) && (rdlane(pv, 21) == 22.0f);
        if (scan_ok) {
            sx = dpp_scan(sx); sy = dpp_scan(sy); sz = dpp_scan(sz);
        } else {
            #pragma unroll
            for (int off = 1; off < 64; off <<= 1) {
                float tx = __shfl_up(sx, off);
                float ty = __shfl_up(sy, off);
                float tz = __shfl_up(sz, off);
                if (l >= off) { sx += tx; sy += ty; sz += tz; }
            }
        }
    }
    if (l == 63) { wtot[w * 3 + 0] = sx; wtot[w * 3 + 1] = sy; wtot[w * 3 + 2] = sz; }
    __syncthreads();

    float ox = 0.f, oy = 0.f, oz = 0.f;
    for (int q = 0; q < w; ++q) {
        ox += wtot[q * 3 + 0]; oy += wtot[q * 3 + 1]; oz += wtot[q * 3 + 2];
    }
    float* outb = out + (size_t)b * (TM1 + 1) * 3;
    if (i < TM1) {
        outb[(i + 1) * 3 + 0] = sx + ox;
        outb[(i + 1) * 3 + 1] = sy + oy;
        outb[(i + 1) * 3 + 2] = sz + oz;
    }
    if (tid == 0) { outb[0] = 0.f; outb[1] = 0.f; outb[2] = 0.f; }
}

extern "C" void kernel_launch(void* const* d_in, const int* in_sizes, int n_in,
                              void* d_out, int out_size, void* d_ws, size_t ws_size,
                              hipStream_t stream)
{
    const float* alpha     = (const float*)d_in[0];
    const float* tau       = (const float*)d_in[1];
    const float* diffusion = (const float*)d_in[2];
    const float* du        = (const float*)d_in[3];
    float* out = (float*)d_out;
    const int BS = in_sizes[0];

    fbm_schur_kernel<<<dim3(BS), dim3(NTH), 0, stream>>>(
        alpha, tau, diffusion, du, out);
}